// Round 8
// baseline (185.533 us; speedup 1.0000x reference)
//
#include <hip/hip_runtime.h>
#include <cstdint>
#include <cstddef>

// Only layer i=1 is live (reference loop re-reads x, so layer 0 is dead code).
// B=8, S=512, D=1024, H=16, DH=64. All GEMMs are M=4096, K=1024.

typedef __attribute__((ext_vector_type(8))) short bf16x8;
typedef __attribute__((ext_vector_type(4))) short bf16x4;
typedef __attribute__((ext_vector_type(4))) float f32x4;

#define MFMA16(a, b, c) __builtin_amdgcn_mfma_f32_16x16x32_bf16((a), (b), (c), 0, 0, 0)

__device__ __forceinline__ unsigned short f2b(float f) {
  union { float f; unsigned int u; } x; x.f = f;
  unsigned int r = x.u + 0x7fffu + ((x.u >> 16) & 1u);
  return (unsigned short)(r >> 16);
}

__device__ __forceinline__ void gl_lds16(const void* g, void* l) {
  __builtin_amdgcn_global_load_lds(
      (const __attribute__((address_space(1))) void*)g,
      (__attribute__((address_space(3))) void*)l, 16, 0, 0);
}

// ---------------------------------------------------------------------------
// GEMM v4: C[M][N] = A[M][K] @ B[N][K]^T (both K-major bf16).
// BM=128, BK=32, BN templated. 3-deep pipelined staging with COUNTED vmcnt
// (T3+T4) AND small static LDS so 2 blocks/CU survive the 64KB granule:
//   BN=64: 3x(8K A + 4K B) = 36KB;  BN=128: 3x(8K+8K) = 48KB.
// Stage tile t+2 at step t; wait vmcnt(L) (L = one stage's loads: tile t+1
// landed, t+2 in flight) + raw s_barrier once per K-step; vmcnt(0) only at the
// tail. Pre-swizzled global source keeps LDS linear for global_load_lds;
// 2-bit chunk XOR (row&3) limits ds_read conflicts to 4-way (1.58x, accepted).
// 1D grid, bijective XCD-aware mapping (xcd=bid&7 owns an 8m x nnHalf region).
// EPI: 0 = +bias -> f32; 1 = +bias, cols<1024 scaled 1/8 -> bf16; 2 = GELU -> bf16.
// ---------------------------------------------------------------------------
template <int BN, int EPI>
__global__ __launch_bounds__(256) void gemm_t(
    const unsigned short* __restrict__ A, const unsigned short* __restrict__ B,
    const float* __restrict__ bias, float* __restrict__ outF,
    unsigned short* __restrict__ outB, int N, int K, int nnHalf) {
  __shared__ char la[3 * 128 * 64];   // 24KB: 3 x [128 rows][64 B]
  __shared__ char lb[3 * BN * 64];    // 12KB (BN=64) / 24KB (BN=128)
  constexpr int NR = BN / 32;         // n-fragments per wave
  constexpr int LPS = 2 + BN / 64;    // loads per thread per stage (A=2, B=1|2)
  const int tid = threadIdx.x;
  const int l = tid & 63, w = tid >> 6;
  const int l15 = l & 15, l4 = l >> 4;
  const int xcd = blockIdx.x & 7, r = blockIdx.x >> 3;
  const int m0 = ((xcd >> 1) * 8 + (r & 7)) * 128;
  const int n0 = ((xcd & 1) * nnHalf + (r >> 3)) * BN;
  const int wr = (w >> 1) * 64, wc = (w & 1) * (BN / 2);
  const int NT = K >> 5;  // K-steps of 32

  // staging: slot c -> row=c>>2, lds chunk=c&3, global chunk=(c&3)^(row&3)
#define STAGE(buf, t)                                                         \
  {                                                                           \
    const int k0_ = (t) * 32;                                                 \
    _Pragma("unroll") for (int i = 0; i < 2; ++i) {                           \
      const int c = i * 256 + tid;                                            \
      const int row = c >> 2;                                                 \
      const int gch = (c & 3) ^ (row & 3);                                    \
      gl_lds16(A + (size_t)(m0 + row) * K + k0_ + gch * 8,                    \
               la + (buf) * 8192 + c * 16);                                   \
    }                                                                         \
    _Pragma("unroll") for (int i = 0; i < BN / 64; ++i) {                     \
      const int c = i * 256 + tid;                                            \
      const int row = c >> 2;                                                 \
      const int gch = (c & 3) ^ (row & 3);                                    \
      gl_lds16(B + (size_t)(n0 + row) * K + k0_ + gch * 8,                    \
               lb + (buf) * (BN * 64) + c * 16);                              \
    }                                                                         \
  }
#define WAIT_L()                                                    \
  {                                                                 \
    if constexpr (LPS == 4) {                                       \
      asm volatile("s_waitcnt vmcnt(4)" ::: "memory");              \
    } else {                                                        \
      asm volatile("s_waitcnt vmcnt(3)" ::: "memory");              \
    }                                                               \
  }

  f32x4 acc[4][NR] = {};
  const unsigned int ch = (unsigned int)((l4 ^ (l15 & 3)) << 4);

  STAGE(0, 0);
  STAGE(1, 1);
  WAIT_L();  // tile 0 landed (tile 1 still in flight)
  __builtin_amdgcn_sched_barrier(0);
  __builtin_amdgcn_s_barrier();
  __builtin_amdgcn_sched_barrier(0);

  int cur = 0, stg = 2;
  for (int t = 0; t < NT; ++t) {
    if (t + 2 < NT) {
      STAGE(stg, t + 2);
    }
    __builtin_amdgcn_sched_barrier(0);
    const char* abuf = la + cur * 8192;
    const char* bbuf = lb + cur * (BN * 64);
    bf16x8 af[4], bfr[NR];
#pragma unroll
    for (int m = 0; m < 4; ++m)
      af[m] = *(const bf16x8*)(abuf + (wr + m * 16 + l15) * 64 + ch);
#pragma unroll
    for (int n = 0; n < NR; ++n)
      bfr[n] = *(const bf16x8*)(bbuf + (wc + n * 16 + l15) * 64 + ch);
#pragma unroll
    for (int m = 0; m < 4; ++m) {
#pragma unroll
      for (int n = 0; n < NR; ++n) {
        acc[m][n] = MFMA16(af[m], bfr[n], acc[m][n]);
      }
    }
    if (t < NT - 1) {
      if (t + 2 < NT) {
        WAIT_L();  // tile t+1 landed; tile t+2 still in flight
      } else {
        asm volatile("s_waitcnt vmcnt(0)" ::: "memory");  // tail drain
      }
      __builtin_amdgcn_sched_barrier(0);
      __builtin_amdgcn_s_barrier();
      __builtin_amdgcn_sched_barrier(0);
    }
    cur = (cur == 2) ? 0 : cur + 1;
    stg = (stg == 2) ? 0 : stg + 1;
  }
#undef STAGE
#undef WAIT_L

#pragma unroll
  for (int m = 0; m < 4; ++m) {
#pragma unroll
    for (int n = 0; n < NR; ++n) {
      const int col = n0 + wc + n * 16 + l15;
      const float bb = bias[col];
#pragma unroll
      for (int e = 0; e < 4; ++e) {
        const int row = m0 + wr + m * 16 + l4 * 4 + e;
        float v = acc[m][n][e] + bb;
        if (EPI == 0) {
          outF[(size_t)row * N + col] = v;
        } else if (EPI == 1) {
          if (col < 1024) v *= 0.125f;  // fold 1/sqrt(DH) into Q
          outB[(size_t)row * N + col] = f2b(v);
        } else {
          v = 0.5f * v * (1.f + erff(v * 0.70710678118654752f));
          outB[(size_t)row * N + col] = f2b(v);
        }
      }
    }
  }
}

// ---------------------------------------------------------------------------
// Attention v5 (unchanged, passing): flash-tiled, double-buffered LDS staging
// of K AND V, XCD-local b=bid&7 mapping, swizzled K/V^T, T14 split.
// ---------------------------------------------------------------------------
__global__ __launch_bounds__(256, 2) void attn_kernel(
    const unsigned short* __restrict__ qkv, const int* __restrict__ mask,
    unsigned short* __restrict__ ctx) {
  extern __shared__ char smem[];
  float* maskadd = (float*)(smem + 65536);  // [512]
  const int bid = blockIdx.x;
  const int b = bid & 7, h = (bid >> 3) & 15, qt = bid >> 7;
  const int tid = threadIdx.x, l = tid & 63, w = tid >> 6;
  const int l15 = l & 15, l4 = l >> 4;
  const size_t RB = (size_t)b * 512 * 3072;

  for (int s = tid; s < 512; s += 256)
    maskadd[s] = mask[b * 512 + s] ? 0.f : -1e18f;

  const unsigned short* Kbase = qkv + RB + 1024 + h * 64;
  const unsigned short* Vbase = qkv + RB + 2048 + h * 64;

  const int kr0 = tid >> 2, kc0 = tid & 3;
  const unsigned int swzk = (unsigned int)((kr0 & 7) << 4);
  const unsigned int ka0 = ((unsigned int)(kr0 * 128 + kc0 * 16)) ^ swzk;
  const unsigned int ka1 = ((unsigned int)(kr0 * 128 + kc0 * 16 + 64)) ^ swzk;
  const int vs0 = 2 * l, vd0 = w * 16;

  bf16x8 k00, k01, k10, k11, vreg[4];
  k00 = *(const bf16x8*)(Kbase + (size_t)kr0 * 3072 + kc0 * 8);
  k01 = *(const bf16x8*)(Kbase + (size_t)kr0 * 3072 + kc0 * 8 + 32);
  k10 = *(const bf16x8*)(Kbase + (size_t)(kr0 + 64) * 3072 + kc0 * 8);
  k11 = *(const bf16x8*)(Kbase + (size_t)(kr0 + 64) * 3072 + kc0 * 8 + 32);
  vreg[0] = *(const bf16x8*)(Vbase + (size_t)vs0 * 3072 + vd0);
  vreg[1] = *(const bf16x8*)(Vbase + (size_t)vs0 * 3072 + vd0 + 8);
  vreg[2] = *(const bf16x8*)(Vbase + (size_t)(vs0 + 1) * 3072 + vd0);
  vreg[3] = *(const bf16x8*)(Vbase + (size_t)(vs0 + 1) * 3072 + vd0 + 8);

  const int q0 = qt * 64 + w * 16;
  const unsigned short* qb =
      qkv + RB + (size_t)(q0 + l15) * 3072 + h * 64 + l4 * 8;
  const bf16x8 qf0 = *(const bf16x8*)(qb);
  const bf16x8 qf1 = *(const bf16x8*)(qb + 32);

#define KWRITE(dst)                        \
  {                                        \
    *(bf16x8*)((dst) + ka0) = k00;         \
    *(bf16x8*)((dst) + ka1) = k01;         \
    *(bf16x8*)((dst) + ka0 + 8192) = k10;  \
    *(bf16x8*)((dst) + ka1 + 8192) = k11;  \
  }
#define VWRITE(dst)                                                          \
  {                                                                          \
    _Pragma("unroll") for (int j = 0; j < 16; ++j) {                         \
      const unsigned short lo_ =                                             \
          (unsigned short)((j < 8) ? vreg[0][j] : vreg[1][j - 8]);           \
      const unsigned short hi_ =                                             \
          (unsigned short)((j < 8) ? vreg[2][j] : vreg[3][j - 8]);           \
      *(unsigned int*)((dst) +                                               \
                       (((vd0 + j) * 256 + vs0 * 2) ^ ((j & 7) << 4))) =     \
          (unsigned int)lo_ | ((unsigned int)hi_ << 16);                     \
    }                                                                        \
  }

  KWRITE(smem);
  VWRITE(smem + 32768);
  __syncthreads();

  const int hi4 = l4 >> 1, gl = l4 & 1, g2 = l4 & 2;
  f32x4 acc[4] = {};
  float run_m = -1e30f, run_s = 0.f;

#pragma unroll
  for (int t = 0; t < 4; ++t) {
    char* kcur = smem + (t & 1) * 16384;
    char* vcur = smem + 32768 + (t & 1) * 16384;
    if (t < 3) {
      const int sn = (t + 1) * 128;
      k00 = *(const bf16x8*)(Kbase + (size_t)(sn + kr0) * 3072 + kc0 * 8);
      k01 = *(const bf16x8*)(Kbase + (size_t)(sn + kr0) * 3072 + kc0 * 8 + 32);
      k10 = *(const bf16x8*)(Kbase + (size_t)(sn + kr0 + 64) * 3072 + kc0 * 8);
      k11 = *(const bf16x8*)(Kbase + (size_t)(sn + kr0 + 64) * 3072 + kc0 * 8 + 32);
      vreg[0] = *(const bf16x8*)(Vbase + (size_t)(sn + vs0) * 3072 + vd0);
      vreg[1] = *(const bf16x8*)(Vbase + (size_t)(sn + vs0) * 3072 + vd0 + 8);
      vreg[2] = *(const bf16x8*)(Vbase + (size_t)(sn + vs0 + 1) * 3072 + vd0);
      vreg[3] = *(const bf16x8*)(Vbase + (size_t)(sn + vs0 + 1) * 3072 + vd0 + 8);
      __builtin_amdgcn_sched_barrier(0);
    }
    f32x4 sc[8];
    __builtin_amdgcn_s_setprio(1);
#pragma unroll
    for (int kk = 0; kk < 8; ++kk) {
      const unsigned int lin = (unsigned int)((kk * 16 + l15) * 128 + l4 * 16);
      const unsigned int swz = (unsigned int)((l15 & 7) << 4);
      const bf16x8 af0 = *(const bf16x8*)(kcur + (lin ^ swz));
      const bf16x8 af1 = *(const bf16x8*)(kcur + ((lin + 64) ^ swz));
      f32x4 c = {0.f, 0.f, 0.f, 0.f};
      c = MFMA16(af0, qf0, c);
      c = MFMA16(af1, qf1, c);
      sc[kk] = c;
    }
    __builtin_amdgcn_s_setprio(0);
    float tmx = -1e30f;
#pragma unroll
    for (int kk = 0; kk < 8; ++kk) {
#pragma unroll
      for (int e = 0; e < 4; ++e) {
        const float v = sc[kk][e] + maskadd[t * 128 + kk * 16 + l4 * 4 + e];
        sc[kk][e] = v;
        tmx = fmaxf(tmx, v);
      }
    }
    tmx = fmaxf(tmx, __shfl_xor(tmx, 16));
    tmx = fmaxf(tmx, __shfl_xor(tmx, 32));
    const float nm = (t == 0) ? tmx : fmaxf(run_m, tmx);
    float tsum = 0.f;
    unsigned int pk[8][2];
#pragma unroll
    for (int kk = 0; kk < 8; ++kk) {
      const float p0 = __expf(sc[kk][0] - nm);
      const float p1 = __expf(sc[kk][1] - nm);
      const float p2 = __expf(sc[kk][2] - nm);
      const float p3 = __expf(sc[kk][3] - nm);
      tsum += (p0 + p1) + (p2 + p3);
      asm("v_cvt_pk_bf16_f32 %0, %1, %2" : "=v"(pk[kk][0]) : "v"(p0), "v"(p1));
      asm("v_cvt_pk_bf16_f32 %0, %1, %2" : "=v"(pk[kk][1]) : "v"(p2), "v"(p3));
    }
    tsum += __shfl_xor(tsum, 16);
    tsum += __shfl_xor(tsum, 32);
    if (t == 0) {
      run_s = tsum;
    } else {
      const float scale = __expf(run_m - nm);
      run_s = run_s * scale + tsum;
      float s4[4];
#pragma unroll
      for (int e = 0; e < 4; ++e) s4[e] = __shfl(scale, l4 * 4 + e);
#pragma unroll
      for (int nt = 0; nt < 4; ++nt) {
#pragma unroll
        for (int e = 0; e < 4; ++e) acc[nt][e] *= s4[e];
      }
    }
    run_m = nm;
#pragma unroll
    for (int k2 = 0; k2 < 4; ++k2) {
      const unsigned int own0 = hi4 ? pk[2 * k2 + 1][0] : pk[2 * k2][0];
      const unsigned int own1 = hi4 ? pk[2 * k2 + 1][1] : pk[2 * k2][1];
      const unsigned int oth0 = hi4 ? pk[2 * k2][0] : pk[2 * k2 + 1][0];
      const unsigned int oth1 = hi4 ? pk[2 * k2][1] : pk[2 * k2 + 1][1];
      const unsigned int s16_0 = (unsigned int)__shfl_xor((int)own0, 16);
      const unsigned int s16_1 = (unsigned int)__shfl_xor((int)own1, 16);
      const unsigned int s32_0 = (unsigned int)__shfl_xor((int)oth0, 32);
      const unsigned int s32_1 = (unsigned int)__shfl_xor((int)oth1, 32);
      const unsigned int s48_0 = (unsigned int)__shfl_xor((int)oth0, 48);
      const unsigned int s48_1 = (unsigned int)__shfl_xor((int)oth1, 48);
      union { unsigned int u[4]; bf16x8 v; } pa;
      pa.u[0] = g2 ? (gl ? s16_0 : s32_0) : (gl ? s48_0 : own0);
      pa.u[1] = g2 ? (gl ? s16_1 : s32_1) : (gl ? s48_1 : own1);
      pa.u[2] = g2 ? (gl ? own0 : s48_0) : (gl ? s32_0 : s16_0);
      pa.u[3] = g2 ? (gl ? own1 : s48_1) : (gl ? s32_1 : s16_1);
      __builtin_amdgcn_s_setprio(1);
#pragma unroll
      for (int nt = 0; nt < 4; ++nt) {
        const int d = nt * 16 + l15;
        const unsigned int vb =
            (unsigned int)((d * 256 + k2 * 64 + l4 * 16) ^ ((l15 & 7) << 4));
        const bf16x8 vbf = *(const bf16x8*)(vcur + vb);
        acc[nt] = MFMA16(pa.v, vbf, acc[nt]);
      }
      __builtin_amdgcn_s_setprio(0);
    }
    if (t < 3) {
      char* knxt = smem + ((t + 1) & 1) * 16384;
      char* vnxt = smem + 32768 + ((t + 1) & 1) * 16384;
      KWRITE(knxt);
      VWRITE(vnxt);
      __syncthreads();
    }
  }
#undef KWRITE
#undef VWRITE

  const float inv = 1.f / run_s;
  float invq[4];
#pragma unroll
  for (int e = 0; e < 4; ++e) invq[e] = __shfl(inv, l4 * 4 + e);
#pragma unroll
  for (int nt = 0; nt < 4; ++nt) {
#pragma unroll
    for (int e = 0; e < 4; ++e) {
      const size_t row = (size_t)b * 512 + q0 + l4 * 4 + e;
      ctx[row * 1024 + h * 64 + nt * 16 + l15] = f2b(acc[nt][e] * invq[e]);
    }
  }
}

// ---------------------------------------------------------------------------
// Custom LayerNorm (unbiased std, eps added to std), optional residual,
// optional +PE, dual f32/bf16 outputs. One block per row.
// ---------------------------------------------------------------------------
__global__ __launch_bounds__(256) void ln_kernel(
    const float* __restrict__ A, const float* __restrict__ R,
    const float* __restrict__ g, const float* __restrict__ bta,
    float* __restrict__ outF, unsigned short* __restrict__ outB, int addPE) {
  __shared__ float red[8];
  const int row = blockIdx.x, tid = threadIdx.x;
  const size_t base = (size_t)row * 1024 + tid * 4;
  float4 a = *(const float4*)(A + base);
  if (R) {
    const float4 r = *(const float4*)(R + base);
    a.x += r.x; a.y += r.y; a.z += r.z; a.w += r.w;
  }
  float s = a.x + a.y + a.z + a.w;
  float q = a.x * a.x + a.y * a.y + a.z * a.z + a.w * a.w;
#pragma unroll
  for (int o = 32; o; o >>= 1) {
    s += __shfl_xor(s, o);
    q += __shfl_xor(q, o);
  }
  if ((tid & 63) == 0) {
    red[(tid >> 6) * 2] = s;
    red[(tid >> 6) * 2 + 1] = q;
  }
  __syncthreads();
  const float S = red[0] + red[2] + red[4] + red[6];
  const float Qs = red[1] + red[3] + red[5] + red[7];
  const float mean = S * (1.f / 1024.f);
  float var = (Qs - 1024.f * mean * mean) * (1.f / 1023.f);
  var = fmaxf(var, 0.f);
  const float inv = 1.f / (sqrtf(var) + 1e-6f);
  float o4[4] = {a.x, a.y, a.z, a.w};
#pragma unroll
  for (int j = 0; j < 4; ++j) {
    const int col = tid * 4 + j;
    float y = g[col] * (o4[j] - mean) * inv + bta[col];
    if (addPE) {
      const float ang = (float)(row & 511) * exp2f((float)col * -0.025952563241307518f);
      y += (col & 1) ? cosf(ang) : sinf(ang);
    }
    o4[j] = y;
  }
  *(float4*)(outF + base) = make_float4(o4[0], o4[1], o4[2], o4[3]);
  if (outB) {
    bf16x4 pb;
    pb[0] = (short)f2b(o4[0]);
    pb[1] = (short)f2b(o4[1]);
    pb[2] = (short)f2b(o4[2]);
    pb[3] = (short)f2b(o4[3]);
    *(bf16x4*)(outB + base) = pb;
  }
}

// ---------------------------------------------------------------------------
// Fused weight prep: 6 f32->bf16 matrix converts + QKV bias pack, one launch.
// ---------------------------------------------------------------------------
__global__ __launch_bounds__(256) void prep_weights(
    const float* __restrict__ Wq, const float* __restrict__ Wk,
    const float* __restrict__ Wv, const float* __restrict__ Wo,
    const float* __restrict__ W1, const float* __restrict__ W2,
    const float* __restrict__ bq, const float* __restrict__ bk,
    const float* __restrict__ bv, unsigned short* __restrict__ wqkv,
    unsigned short* __restrict__ wo, unsigned short* __restrict__ w1,
    unsigned short* __restrict__ w2, float* __restrict__ bqkv) {
  const int gid = blockIdx.x * 256 + threadIdx.x;
  if (gid < 1572864) {
    const int chunk = gid >> 18;
    const int off = (gid & 262143) * 4;
    const float* s;
    unsigned short* d;
    switch (chunk) {
      case 0: s = Wq; d = wqkv; break;
      case 1: s = Wk; d = wqkv + 1048576; break;
      case 2: s = Wv; d = wqkv + 2097152; break;
      case 3: s = Wo; d = wo; break;
      case 4: s = W1; d = w1; break;
      default: s = W2; d = w2; break;
    }
    const float4 v = *(const float4*)(s + off);
    bf16x4 o;
    o[0] = (short)f2b(v.x); o[1] = (short)f2b(v.y);
    o[2] = (short)f2b(v.z); o[3] = (short)f2b(v.w);
    *(bf16x4*)(d + off) = o;
  } else {
    const int idx = (gid - 1572864) * 4;
    if (idx < 3072) {
      const float* bs = idx < 1024 ? bq : (idx < 2048 ? bk - 1024 : bv - 2048);
      *(float4*)(bqkv + idx) = *(const float4*)(bs + idx);
    }
  }
}

extern "C" void kernel_launch(void* const* d_in, const int* in_sizes, int n_in,
                              void* d_out, int out_size, void* d_ws, size_t ws_size,
                              hipStream_t stream) {
  (void)in_sizes; (void)n_in; (void)out_size; (void)ws_size;
  const float* features = (const float*)d_in[0];
  const int* mask = (const int*)d_in[1];
  const float* ln_in_g = (const float*)d_in[2];
  const float* ln_in_b = (const float*)d_in[3];
  const size_t DD = 1024 * 1024;
  // layer index 1 (the only live layer)
  const float* Wq = (const float*)d_in[4] + DD;
  const float* bq = (const float*)d_in[5] + 1024;
  const float* Wk = (const float*)d_in[6] + DD;
  const float* bk = (const float*)d_in[7] + 1024;
  const float* Wv = (const float*)d_in[8] + DD;
  const float* bv = (const float*)d_in[9] + 1024;
  const float* Wo = (const float*)d_in[10] + DD;
  const float* bo = (const float*)d_in[11] + 1024;
  const float* l1g = (const float*)d_in[12] + 1024;
  const float* l1b = (const float*)d_in[13] + 1024;
  const float* W1 = (const float*)d_in[14] + DD;
  const float* b1 = (const float*)d_in[15] + 1024;
  const float* W2 = (const float*)d_in[16] + DD;
  const float* b2 = (const float*)d_in[17] + 1024;
  const float* l2g = (const float*)d_in[18] + 1024;
  const float* l2b = (const float*)d_in[19] + 1024;

  char* base = (char*)d_ws;
  float* x_f32 = (float*)(base);                              // 16 MB
  float* tmp_f32 = (float*)(base + 16777216);                 // 16 MB
  float* s_f32 = (float*)(base + 33554432);                   // 16 MB
  unsigned short* qkv = (unsigned short*)(base + 50331648);   // 24 MB [4096][3072]
  unsigned short* xb = (unsigned short*)(base + 75497472);    // 8 MB (x_bf16, later h)
  unsigned short* ctxb = (unsigned short*)(base + 83886080);  // 8 MB (ctx, later s_bf16)
  unsigned short* wqkv = (unsigned short*)(base + 92274688);  // 6 MB [3072][1024]
  unsigned short* wo = (unsigned short*)(base + 98566144);    // 2 MB
  unsigned short* w1 = (unsigned short*)(base + 100663296);   // 2 MB
  unsigned short* w2 = (unsigned short*)(base + 102760448);   // 2 MB
  float* bqkv = (float*)(base + 104857600);                   // 12 KB

  hipFuncSetAttribute((const void*)attn_kernel,
                      hipFuncAttributeMaxDynamicSharedMemorySize, 67584);

  prep_weights<<<6147, 256, 0, stream>>>(Wq, Wk, Wv, Wo, W1, W2, bq, bk, bv,
                                         wqkv, wo, w1, w2, bqkv);
  // x = LN(features) + PE  -> f32 + bf16
  ln_kernel<<<4096, 256, 0, stream>>>(features, nullptr, ln_in_g, ln_in_b, x_f32, xb, 1);
  // fused QKV projection (Q pre-scaled by 1/8): 32m x 24n tiles = 768 blocks
  gemm_t<128, 1><<<768, 256, 0, stream>>>(xb, wqkv, bqkv, nullptr, qkv, 3072, 1024, 12);
  // attention
  attn_kernel<<<1024, 256, 67584, stream>>>(qkv, mask, ctxb);
  // attn_out = ctx @ Wo^T + bo : BN=64, 32m x 16n = 512 blocks
  gemm_t<64, 0><<<512, 256, 0, stream>>>(ctxb, wo, bo, tmp_f32, nullptr, 1024, 1024, 8);
  // s = LN(attn_out + x)
  ln_kernel<<<4096, 256, 0, stream>>>(tmp_f32, x_f32, l1g, l1b, s_f32, ctxb, 0);
  // h = gelu(s @ W1^T + b1)
  gemm_t<64, 2><<<512, 256, 0, stream>>>(ctxb, w1, b1, nullptr, xb, 1024, 1024, 8);
  // f = h @ W2^T + b2
  gemm_t<64, 0><<<512, 256, 0, stream>>>(xb, w2, b2, tmp_f32, nullptr, 1024, 1024, 8);
  // out = LN(f + s)
  ln_kernel<<<4096, 256, 0, stream>>>(tmp_f32, s_f32, l2g, l2b, (float*)d_out, nullptr, 0);
}

// Round 9
// 154.951 us; speedup vs baseline: 1.1974x; 1.1974x over previous
//
#include <hip/hip_runtime.h>
#include <cstdint>
#include <cstddef>

// Only layer i=1 is live (reference loop re-reads x, so layer 0 is dead code).
// B=8, S=512, D=1024, H=16, DH=64. All GEMMs are M=4096, K=1024.
// All intermediates bf16 (residuals included); only final LN writes f32.

typedef __attribute__((ext_vector_type(8))) short bf16x8;
typedef __attribute__((ext_vector_type(4))) short bf16x4;
typedef __attribute__((ext_vector_type(4))) float f32x4;

#define MFMA16(a, b, c) __builtin_amdgcn_mfma_f32_16x16x32_bf16((a), (b), (c), 0, 0, 0)

__device__ __forceinline__ unsigned short f2b(float f) {
  union { float f; unsigned int u; } x; x.f = f;
  unsigned int r = x.u + 0x7fffu + ((x.u >> 16) & 1u);
  return (unsigned short)(r >> 16);
}

__device__ __forceinline__ float b2f(unsigned short u) {
  union { unsigned int i; float f; } x;
  x.i = ((unsigned int)u) << 16;
  return x.f;
}

__device__ __forceinline__ void gl_lds16(const void* g, void* l) {
  __builtin_amdgcn_global_load_lds(
      (const __attribute__((address_space(1))) void*)g,
      (__attribute__((address_space(3))) void*)l, 16, 0, 0);
}

// ---------------------------------------------------------------------------
// GEMM (r7 config verbatim — best e2e 172.9): BM=128, BK=64, BN templated.
// 3-deep pipelined staging, COUNTED vmcnt (tile t+1 landed, t+2 in flight),
// raw s_barrier once per K-step, vmcnt(0) only at tail. Pre-swizzled global
// source keeps LDS linear for global_load_lds; ds_read conflict-free.
// EPI: 1 = +bias, cols<1024 scaled 1/8 -> bf16; 2 = GELU -> bf16;
//      3 = +bias -> bf16.
// ---------------------------------------------------------------------------
template <int BN, int EPI>
__global__ __launch_bounds__(256) void gemm_t(
    const unsigned short* __restrict__ A, const unsigned short* __restrict__ B,
    const float* __restrict__ bias, unsigned short* __restrict__ outB, int N,
    int K, int nnHalf) {
  extern __shared__ char smem[];
  char* la = smem;              // 3 x [128 rows][128 B]
  char* lb = smem + 3 * 16384;  // 3 x [BN rows][128 B]
  constexpr int NR = BN / 32;
  const int tid = threadIdx.x;
  const int l = tid & 63, w = tid >> 6;
  const int l15 = l & 15, l4 = l >> 4;
  const int xcd = blockIdx.x & 7, r = blockIdx.x >> 3;
  const int m0 = ((xcd >> 1) * 8 + (r & 7)) * 128;
  const int n0 = ((xcd & 1) * nnHalf + (r >> 3)) * BN;
  const int wr = (w >> 1) * 64, wc = (w & 1) * (BN / 2);
  const int NT = K >> 6;  // K-steps of 64

#define STAGE(buf, t)                                                         \
  {                                                                           \
    const int k0_ = (t) * 64;                                                 \
    _Pragma("unroll") for (int i = 0; i < 4; ++i) {                           \
      const int c = i * 256 + tid;                                            \
      const int row = c >> 3;                                                 \
      const int gch = (c & 7) ^ (row & 7);                                    \
      gl_lds16(A + (size_t)(m0 + row) * K + k0_ + gch * 8,                    \
               la + (buf) * 16384 + (i * 256 + w * 64) * 16);                 \
    }                                                                         \
    _Pragma("unroll") for (int i = 0; i < BN / 32; ++i) {                     \
      const int c = i * 256 + tid;                                            \
      const int row = c >> 3;                                                 \
      const int gch = (c & 7) ^ (row & 7);                                    \
      gl_lds16(B + (size_t)(n0 + row) * K + k0_ + gch * 8,                    \
               lb + (buf) * (BN * 128) + (i * 256 + w * 64) * 16);            \
    }                                                                         \
  }
#define WAIT_L()                                                   \
  {                                                                \
    if constexpr (BN == 128) {                                     \
      asm volatile("s_waitcnt vmcnt(8)" ::: "memory");             \
    } else {                                                       \
      asm volatile("s_waitcnt vmcnt(6)" ::: "memory");             \
    }                                                              \
  }

  f32x4 acc[4][NR] = {};
  const int sw = l15 & 7;

  STAGE(0, 0);
  STAGE(1, 1);
  WAIT_L();  // tile 0 landed (tile 1 still in flight)
  __builtin_amdgcn_sched_barrier(0);
  __builtin_amdgcn_s_barrier();
  __builtin_amdgcn_sched_barrier(0);

  for (int t = 0; t < NT; ++t) {
    if (t + 2 < NT) {
      STAGE((t + 2) % 3, t + 2);
    }
    __builtin_amdgcn_sched_barrier(0);
    const char* abuf = la + (t % 3) * 16384;
    const char* bbuf = lb + (t % 3) * (BN * 128);
#pragma unroll
    for (int kk = 0; kk < 2; ++kk) {
      const unsigned int ch = (unsigned int)(((kk * 4 + l4) ^ sw) << 4);
      bf16x8 af[4], bfr[NR];
#pragma unroll
      for (int m = 0; m < 4; ++m)
        af[m] = *(const bf16x8*)(abuf + (wr + m * 16 + l15) * 128 + ch);
#pragma unroll
      for (int n = 0; n < NR; ++n)
        bfr[n] = *(const bf16x8*)(bbuf + (wc + n * 16 + l15) * 128 + ch);
#pragma unroll
      for (int m = 0; m < 4; ++m) {
#pragma unroll
        for (int n = 0; n < NR; ++n) {
          acc[m][n] = MFMA16(af[m], bfr[n], acc[m][n]);
        }
      }
    }
    if (t < NT - 1) {
      if (t + 2 < NT) {
        WAIT_L();  // tile t+1 landed; tile t+2 still in flight
      } else {
        asm volatile("s_waitcnt vmcnt(0)" ::: "memory");  // tail drain
      }
      __builtin_amdgcn_sched_barrier(0);
      __builtin_amdgcn_s_barrier();
      __builtin_amdgcn_sched_barrier(0);
    }
  }
#undef STAGE
#undef WAIT_L

#pragma unroll
  for (int m = 0; m < 4; ++m) {
#pragma unroll
    for (int n = 0; n < NR; ++n) {
      const int col = n0 + wc + n * 16 + l15;
      const float bb = bias[col];
#pragma unroll
      for (int e = 0; e < 4; ++e) {
        const int row = m0 + wr + m * 16 + l4 * 4 + e;
        float v = acc[m][n][e] + bb;
        if (EPI == 1) {
          if (col < 1024) v *= 0.125f;  // fold 1/sqrt(DH) into Q
        } else if (EPI == 2) {
          v = 0.5f * v * (1.f + erff(v * 0.70710678118654752f));
        }
        outB[(size_t)row * N + col] = f2b(v);
      }
    }
  }
}

// ---------------------------------------------------------------------------
// Attention v5 (unchanged, passing): flash-tiled, double-buffered LDS staging
// of K AND V, XCD-local b=bid&7 mapping, swizzled K/V^T, T14 split.
// ---------------------------------------------------------------------------
__global__ __launch_bounds__(256, 2) void attn_kernel(
    const unsigned short* __restrict__ qkv, const int* __restrict__ mask,
    unsigned short* __restrict__ ctx) {
  extern __shared__ char smem[];
  float* maskadd = (float*)(smem + 65536);  // [512]
  const int bid = blockIdx.x;
  const int b = bid & 7, h = (bid >> 3) & 15, qt = bid >> 7;
  const int tid = threadIdx.x, l = tid & 63, w = tid >> 6;
  const int l15 = l & 15, l4 = l >> 4;
  const size_t RB = (size_t)b * 512 * 3072;

  for (int s = tid; s < 512; s += 256)
    maskadd[s] = mask[b * 512 + s] ? 0.f : -1e18f;

  const unsigned short* Kbase = qkv + RB + 1024 + h * 64;
  const unsigned short* Vbase = qkv + RB + 2048 + h * 64;

  const int kr0 = tid >> 2, kc0 = tid & 3;
  const unsigned int swzk = (unsigned int)((kr0 & 7) << 4);
  const unsigned int ka0 = ((unsigned int)(kr0 * 128 + kc0 * 16)) ^ swzk;
  const unsigned int ka1 = ((unsigned int)(kr0 * 128 + kc0 * 16 + 64)) ^ swzk;
  const int vs0 = 2 * l, vd0 = w * 16;

  bf16x8 k00, k01, k10, k11, vreg[4];
  k00 = *(const bf16x8*)(Kbase + (size_t)kr0 * 3072 + kc0 * 8);
  k01 = *(const bf16x8*)(Kbase + (size_t)kr0 * 3072 + kc0 * 8 + 32);
  k10 = *(const bf16x8*)(Kbase + (size_t)(kr0 + 64) * 3072 + kc0 * 8);
  k11 = *(const bf16x8*)(Kbase + (size_t)(kr0 + 64) * 3072 + kc0 * 8 + 32);
  vreg[0] = *(const bf16x8*)(Vbase + (size_t)vs0 * 3072 + vd0);
  vreg[1] = *(const bf16x8*)(Vbase + (size_t)vs0 * 3072 + vd0 + 8);
  vreg[2] = *(const bf16x8*)(Vbase + (size_t)(vs0 + 1) * 3072 + vd0);
  vreg[3] = *(const bf16x8*)(Vbase + (size_t)(vs0 + 1) * 3072 + vd0 + 8);

  const int q0 = qt * 64 + w * 16;
  const unsigned short* qb =
      qkv + RB + (size_t)(q0 + l15) * 3072 + h * 64 + l4 * 8;
  const bf16x8 qf0 = *(const bf16x8*)(qb);
  const bf16x8 qf1 = *(const bf16x8*)(qb + 32);

#define KWRITE(dst)                        \
  {                                        \
    *(bf16x8*)((dst) + ka0) = k00;         \
    *(bf16x8*)((dst) + ka1) = k01;         \
    *(bf16x8*)((dst) + ka0 + 8192) = k10;  \
    *(bf16x8*)((dst) + ka1 + 8192) = k11;  \
  }
#define VWRITE(dst)                                                          \
  {                                                                          \
    _Pragma("unroll") for (int j = 0; j < 16; ++j) {                         \
      const unsigned short lo_ =                                             \
          (unsigned short)((j < 8) ? vreg[0][j] : vreg[1][j - 8]);           \
      const unsigned short hi_ =                                             \
          (unsigned short)((j < 8) ? vreg[2][j] : vreg[3][j - 8]);           \
      *(unsigned int*)((dst) +                                               \
                       (((vd0 + j) * 256 + vs0 * 2) ^ ((j & 7) << 4))) =     \
          (unsigned int)lo_ | ((unsigned int)hi_ << 16);                     \
    }                                                                        \
  }

  KWRITE(smem);
  VWRITE(smem + 32768);
  __syncthreads();

  const int hi4 = l4 >> 1, gl = l4 & 1, g2 = l4 & 2;
  f32x4 acc[4] = {};
  float run_m = -1e30f, run_s = 0.f;

#pragma unroll
  for (int t = 0; t < 4; ++t) {
    char* kcur = smem + (t & 1) * 16384;
    char* vcur = smem + 32768 + (t & 1) * 16384;
    if (t < 3) {
      const int sn = (t + 1) * 128;
      k00 = *(const bf16x8*)(Kbase + (size_t)(sn + kr0) * 3072 + kc0 * 8);
      k01 = *(const bf16x8*)(Kbase + (size_t)(sn + kr0) * 3072 + kc0 * 8 + 32);
      k10 = *(const bf16x8*)(Kbase + (size_t)(sn + kr0 + 64) * 3072 + kc0 * 8);
      k11 = *(const bf16x8*)(Kbase + (size_t)(sn + kr0 + 64) * 3072 + kc0 * 8 + 32);
      vreg[0] = *(const bf16x8*)(Vbase + (size_t)(sn + vs0) * 3072 + vd0);
      vreg[1] = *(const bf16x8*)(Vbase + (size_t)(sn + vs0) * 3072 + vd0 + 8);
      vreg[2] = *(const bf16x8*)(Vbase + (size_t)(sn + vs0 + 1) * 3072 + vd0);
      vreg[3] = *(const bf16x8*)(Vbase + (size_t)(sn + vs0 + 1) * 3072 + vd0 + 8);
      __builtin_amdgcn_sched_barrier(0);
    }
    f32x4 sc[8];
    __builtin_amdgcn_s_setprio(1);
#pragma unroll
    for (int kk = 0; kk < 8; ++kk) {
      const unsigned int lin = (unsigned int)((kk * 16 + l15) * 128 + l4 * 16);
      const unsigned int swz = (unsigned int)((l15 & 7) << 4);
      const bf16x8 af0 = *(const bf16x8*)(kcur + (lin ^ swz));
      const bf16x8 af1 = *(const bf16x8*)(kcur + ((lin + 64) ^ swz));
      f32x4 c = {0.f, 0.f, 0.f, 0.f};
      c = MFMA16(af0, qf0, c);
      c = MFMA16(af1, qf1, c);
      sc[kk] = c;
    }
    __builtin_amdgcn_s_setprio(0);
    float tmx = -1e30f;
#pragma unroll
    for (int kk = 0; kk < 8; ++kk) {
#pragma unroll
      for (int e = 0; e < 4; ++e) {
        const float v = sc[kk][e] + maskadd[t * 128 + kk * 16 + l4 * 4 + e];
        sc[kk][e] = v;
        tmx = fmaxf(tmx, v);
      }
    }
    tmx = fmaxf(tmx, __shfl_xor(tmx, 16));
    tmx = fmaxf(tmx, __shfl_xor(tmx, 32));
    const float nm = (t == 0) ? tmx : fmaxf(run_m, tmx);
    float tsum = 0.f;
    unsigned int pk[8][2];
#pragma unroll
    for (int kk = 0; kk < 8; ++kk) {
      const float p0 = __expf(sc[kk][0] - nm);
      const float p1 = __expf(sc[kk][1] - nm);
      const float p2 = __expf(sc[kk][2] - nm);
      const float p3 = __expf(sc[kk][3] - nm);
      tsum += (p0 + p1) + (p2 + p3);
      asm("v_cvt_pk_bf16_f32 %0, %1, %2" : "=v"(pk[kk][0]) : "v"(p0), "v"(p1));
      asm("v_cvt_pk_bf16_f32 %0, %1, %2" : "=v"(pk[kk][1]) : "v"(p2), "v"(p3));
    }
    tsum += __shfl_xor(tsum, 16);
    tsum += __shfl_xor(tsum, 32);
    if (t == 0) {
      run_s = tsum;
    } else {
      const float scale = __expf(run_m - nm);
      run_s = run_s * scale + tsum;
      float s4[4];
#pragma unroll
      for (int e = 0; e < 4; ++e) s4[e] = __shfl(scale, l4 * 4 + e);
#pragma unroll
      for (int nt = 0; nt < 4; ++nt) {
#pragma unroll
        for (int e = 0; e < 4; ++e) acc[nt][e] *= s4[e];
      }
    }
    run_m = nm;
#pragma unroll
    for (int k2 = 0; k2 < 4; ++k2) {
      const unsigned int own0 = hi4 ? pk[2 * k2 + 1][0] : pk[2 * k2][0];
      const unsigned int own1 = hi4 ? pk[2 * k2 + 1][1] : pk[2 * k2][1];
      const unsigned int oth0 = hi4 ? pk[2 * k2][0] : pk[2 * k2 + 1][0];
      const unsigned int oth1 = hi4 ? pk[2 * k2][1] : pk[2 * k2 + 1][1];
      const unsigned int s16_0 = (unsigned int)__shfl_xor((int)own0, 16);
      const unsigned int s16_1 = (unsigned int)__shfl_xor((int)own1, 16);
      const unsigned int s32_0 = (unsigned int)__shfl_xor((int)oth0, 32);
      const unsigned int s32_1 = (unsigned int)__shfl_xor((int)oth1, 32);
      const unsigned int s48_0 = (unsigned int)__shfl_xor((int)oth0, 48);
      const unsigned int s48_1 = (unsigned int)__shfl_xor((int)oth1, 48);
      union { unsigned int u[4]; bf16x8 v; } pa;
      pa.u[0] = g2 ? (gl ? s16_0 : s32_0) : (gl ? s48_0 : own0);
      pa.u[1] = g2 ? (gl ? s16_1 : s32_1) : (gl ? s48_1 : own1);
      pa.u[2] = g2 ? (gl ? own0 : s48_0) : (gl ? s32_0 : s16_0);
      pa.u[3] = g2 ? (gl ? own1 : s48_1) : (gl ? s32_1 : s16_1);
      __builtin_amdgcn_s_setprio(1);
#pragma unroll
      for (int nt = 0; nt < 4; ++nt) {
        const int d = nt * 16 + l15;
        const unsigned int vb =
            (unsigned int)((d * 256 + k2 * 64 + l4 * 16) ^ ((l15 & 7) << 4));
        const bf16x8 vbf = *(const bf16x8*)(vcur + vb);
        acc[nt] = MFMA16(pa.v, vbf, acc[nt]);
      }
      __builtin_amdgcn_s_setprio(0);
    }
    if (t < 3) {
      char* knxt = smem + ((t + 1) & 1) * 16384;
      char* vnxt = smem + 32768 + ((t + 1) & 1) * 16384;
      KWRITE(knxt);
      VWRITE(vnxt);
      __syncthreads();
    }
  }
#undef KWRITE
#undef VWRITE

  const float inv = 1.f / run_s;
  float invq[4];
#pragma unroll
  for (int e = 0; e < 4; ++e) invq[e] = __shfl(inv, l4 * 4 + e);
#pragma unroll
  for (int nt = 0; nt < 4; ++nt) {
#pragma unroll
    for (int e = 0; e < 4; ++e) {
      const size_t row = (size_t)b * 512 + q0 + l4 * 4 + e;
      ctx[row * 1024 + h * 64 + nt * 16 + l15] = f2b(acc[nt][e] * invq[e]);
    }
  }
}

// ---------------------------------------------------------------------------
// Custom LayerNorm (unbiased std, eps added to std). One block per row.
// MODE 0: A f32, no residual, +PE, out bf16.
// MODE 1: A bf16, R bf16, out bf16.
// MODE 2: A bf16, R bf16, out f32.
// ---------------------------------------------------------------------------
template <int MODE>
__global__ __launch_bounds__(256) void ln_k(
    const void* __restrict__ Ap, const void* __restrict__ Rp,
    const float* __restrict__ g, const float* __restrict__ bta,
    void* __restrict__ outp) {
  __shared__ float red[8];
  const int row = blockIdx.x, tid = threadIdx.x;
  const size_t base = (size_t)row * 1024 + tid * 4;
  float a4[4];
  if (MODE == 0) {
    const float4 a = *(const float4*)((const float*)Ap + base);
    a4[0] = a.x; a4[1] = a.y; a4[2] = a.z; a4[3] = a.w;
  } else {
    const bf16x4 a = *(const bf16x4*)((const unsigned short*)Ap + base);
    const bf16x4 rr = *(const bf16x4*)((const unsigned short*)Rp + base);
#pragma unroll
    for (int j = 0; j < 4; ++j)
      a4[j] = b2f((unsigned short)a[j]) + b2f((unsigned short)rr[j]);
  }
  float s = a4[0] + a4[1] + a4[2] + a4[3];
  float q = a4[0] * a4[0] + a4[1] * a4[1] + a4[2] * a4[2] + a4[3] * a4[3];
#pragma unroll
  for (int o = 32; o; o >>= 1) {
    s += __shfl_xor(s, o);
    q += __shfl_xor(q, o);
  }
  if ((tid & 63) == 0) {
    red[(tid >> 6) * 2] = s;
    red[(tid >> 6) * 2 + 1] = q;
  }
  __syncthreads();
  const float S = red[0] + red[2] + red[4] + red[6];
  const float Qs = red[1] + red[3] + red[5] + red[7];
  const float mean = S * (1.f / 1024.f);
  float var = (Qs - 1024.f * mean * mean) * (1.f / 1023.f);
  var = fmaxf(var, 0.f);
  const float inv = 1.f / (sqrtf(var) + 1e-6f);
  float o4[4];
#pragma unroll
  for (int j = 0; j < 4; ++j) {
    const int col = tid * 4 + j;
    float y = g[col] * (a4[j] - mean) * inv + bta[col];
    if (MODE == 0) {
      const float ang =
          (float)(row & 511) * exp2f((float)col * -0.025952563241307518f);
      y += (col & 1) ? cosf(ang) : sinf(ang);
    }
    o4[j] = y;
  }
  if (MODE == 2) {
    *(float4*)((float*)outp + base) = make_float4(o4[0], o4[1], o4[2], o4[3]);
  } else {
    bf16x4 pb;
    pb[0] = (short)f2b(o4[0]);
    pb[1] = (short)f2b(o4[1]);
    pb[2] = (short)f2b(o4[2]);
    pb[3] = (short)f2b(o4[3]);
    *(bf16x4*)((unsigned short*)outp + base) = pb;
  }
}

// ---------------------------------------------------------------------------
// Fused weight prep: 6 f32->bf16 matrix converts + QKV bias pack, one launch.
// ---------------------------------------------------------------------------
__global__ __launch_bounds__(256) void prep_weights(
    const float* __restrict__ Wq, const float* __restrict__ Wk,
    const float* __restrict__ Wv, const float* __restrict__ Wo,
    const float* __restrict__ W1, const float* __restrict__ W2,
    const float* __restrict__ bq, const float* __restrict__ bk,
    const float* __restrict__ bv, unsigned short* __restrict__ wqkv,
    unsigned short* __restrict__ wo, unsigned short* __restrict__ w1,
    unsigned short* __restrict__ w2, float* __restrict__ bqkv) {
  const int gid = blockIdx.x * 256 + threadIdx.x;
  if (gid < 1572864) {
    const int chunk = gid >> 18;
    const int off = (gid & 262143) * 4;
    const float* s;
    unsigned short* d;
    switch (chunk) {
      case 0: s = Wq; d = wqkv; break;
      case 1: s = Wk; d = wqkv + 1048576; break;
      case 2: s = Wv; d = wqkv + 2097152; break;
      case 3: s = Wo; d = wo; break;
      case 4: s = W1; d = w1; break;
      default: s = W2; d = w2; break;
    }
    const float4 v = *(const float4*)(s + off);
    bf16x4 o;
    o[0] = (short)f2b(v.x); o[1] = (short)f2b(v.y);
    o[2] = (short)f2b(v.z); o[3] = (short)f2b(v.w);
    *(bf16x4*)(d + off) = o;
  } else {
    const int idx = (gid - 1572864) * 4;
    if (idx < 3072) {
      const float* bs = idx < 1024 ? bq : (idx < 2048 ? bk - 1024 : bv - 2048);
      *(float4*)(bqkv + idx) = *(const float4*)(bs + idx);
    }
  }
}

extern "C" void kernel_launch(void* const* d_in, const int* in_sizes, int n_in,
                              void* d_out, int out_size, void* d_ws, size_t ws_size,
                              hipStream_t stream) {
  (void)in_sizes; (void)n_in; (void)out_size; (void)ws_size;
  const float* features = (const float*)d_in[0];
  const int* mask = (const int*)d_in[1];
  const float* ln_in_g = (const float*)d_in[2];
  const float* ln_in_b = (const float*)d_in[3];
  const size_t DD = 1024 * 1024;
  // layer index 1 (the only live layer)
  const float* Wq = (const float*)d_in[4] + DD;
  const float* bq = (const float*)d_in[5] + 1024;
  const float* Wk = (const float*)d_in[6] + DD;
  const float* bk = (const float*)d_in[7] + 1024;
  const float* Wv = (const float*)d_in[8] + DD;
  const float* bv = (const float*)d_in[9] + 1024;
  const float* Wo = (const float*)d_in[10] + DD;
  const float* bo = (const float*)d_in[11] + 1024;
  const float* l1g = (const float*)d_in[12] + 1024;
  const float* l1b = (const float*)d_in[13] + 1024;
  const float* W1 = (const float*)d_in[14] + DD;
  const float* b1 = (const float*)d_in[15] + 1024;
  const float* W2 = (const float*)d_in[16] + DD;
  const float* b2 = (const float*)d_in[17] + 1024;
  const float* l2g = (const float*)d_in[18] + 1024;
  const float* l2b = (const float*)d_in[19] + 1024;

  char* base = (char*)d_ws;
  unsigned short* qkv = (unsigned short*)(base);              // 24 MB [4096][3072]
  unsigned short* xb = (unsigned short*)(base + 25165824);    // 8 MB: x bf16, then h
  unsigned short* ctxb = (unsigned short*)(base + 33554432);  // 8 MB: ctx, then s
  unsigned short* abuf = (unsigned short*)(base + 41943040);  // 8 MB: attn_out, then f
  unsigned short* wqkv = (unsigned short*)(base + 50331648);  // 6 MB [3072][1024]
  unsigned short* wo = (unsigned short*)(base + 56623104);    // 2 MB
  unsigned short* w1 = (unsigned short*)(base + 58720256);    // 2 MB
  unsigned short* w2 = (unsigned short*)(base + 60817408);    // 2 MB
  float* bqkv = (float*)(base + 62914560);                    // 12 KB

  hipFuncSetAttribute((const void*)gemm_t<128, 1>,
                      hipFuncAttributeMaxDynamicSharedMemorySize, 98304);
  hipFuncSetAttribute((const void*)gemm_t<64, 2>,
                      hipFuncAttributeMaxDynamicSharedMemorySize, 73728);
  hipFuncSetAttribute((const void*)gemm_t<64, 3>,
                      hipFuncAttributeMaxDynamicSharedMemorySize, 73728);
  hipFuncSetAttribute((const void*)attn_kernel,
                      hipFuncAttributeMaxDynamicSharedMemorySize, 67584);

  prep_weights<<<6147, 256, 0, stream>>>(Wq, Wk, Wv, Wo, W1, W2, bq, bk, bv,
                                         wqkv, wo, w1, w2, bqkv);
  // x = LN(features) + PE -> bf16
  ln_k<0><<<4096, 256, 0, stream>>>(features, nullptr, ln_in_g, ln_in_b, xb);
  // fused QKV projection (Q pre-scaled by 1/8): 32m x 24n tiles = 768 blocks
  gemm_t<128, 1><<<768, 256, 98304, stream>>>(xb, wqkv, bqkv, qkv, 3072, 1024, 12);
  // attention
  attn_kernel<<<1024, 256, 67584, stream>>>(qkv, mask, ctxb);
  // attn_out = ctx @ Wo^T + bo -> bf16
  gemm_t<64, 3><<<512, 256, 73728, stream>>>(ctxb, wo, bo, abuf, 1024, 1024, 8);
  // s = LN(attn_out + x) -> bf16 (overwrites ctx)
  ln_k<1><<<4096, 256, 0, stream>>>(abuf, xb, l1g, l1b, ctxb);
  // h = gelu(s @ W1^T + b1) -> bf16 (overwrites x)
  gemm_t<64, 2><<<512, 256, 73728, stream>>>(ctxb, w1, b1, xb, 1024, 1024, 8);
  // f = h @ W2^T + b2 -> bf16 (overwrites attn_out)
  gemm_t<64, 3><<<512, 256, 73728, stream>>>(xb, w2, b2, abuf, 1024, 1024, 8);
  // out = LN(f + s) -> f32
  ln_k<2><<<4096, 256, 0, stream>>>(abuf, ctxb, l2g, l2b, (float*)d_out);
}